// Round 10
// baseline (465.047 us; speedup 1.0000x reference)
//
#include <hip/hip_runtime.h>
#include <math.h>

#define HID 128
#define EDGE_D 32
#define SC 0.36067376f  // 0.25 * log2(e)

typedef unsigned short u16;
typedef unsigned int u32;
typedef __bf16 bf16x8 __attribute__((ext_vector_type(8)));
typedef float f32x4 __attribute__((ext_vector_type(4)));
typedef u32 u32x4 __attribute__((ext_vector_type(4)));
typedef u32 u32x2 __attribute__((ext_vector_type(2)));

static __device__ __forceinline__ u16 f2bf(float f) {
  u32 u = __float_as_uint(f);
  u += 0x7fffu + ((u >> 16) & 1u);
  return (u16)(u >> 16);
}
static __device__ __forceinline__ u32 pack2(float a, float b) {
  return (u32)f2bf(a) | ((u32)f2bf(b) << 16);
}
static __device__ __forceinline__ float bflo(u32 w) { return __uint_as_float(w << 16); }
static __device__ __forceinline__ float bfhi(u32 w) { return __uint_as_float(w & 0xffff0000u); }
// all-lanes sum within each 16-lane row via DPP row rotates (pure VALU)
static __device__ __forceinline__ float grp16_sum(float x) {
  x += __int_as_float(__builtin_amdgcn_mov_dpp(__float_as_int(x), 0x128, 0xf, 0xf, true));
  x += __int_as_float(__builtin_amdgcn_mov_dpp(__float_as_int(x), 0x124, 0xf, 0xf, true));
  x += __int_as_float(__builtin_amdgcn_mov_dpp(__float_as_int(x), 0x122, 0xf, 0xf, true));
  x += __int_as_float(__builtin_amdgcn_mov_dpp(__float_as_int(x), 0x121, 0xf, 0xf, true));
  return x;
}
static __device__ __forceinline__ float wave_allreduce_sum(float v) {
#pragma unroll
  for (int off = 32; off > 0; off >>= 1) v += __shfl_xor(v, off);
  return v;
}

// ---------- LayerNorm: out_bf16 = LN(in) ----------
__global__ __launch_bounds__(256) void ln_kernel(const float* __restrict__ in,
                                                 u16* __restrict__ out,
                                                 const float* __restrict__ w,
                                                 const float* __restrict__ b, int n) {
  int row0 = blockIdx.x * 4 + (threadIdx.x >> 6);
  int lane = threadIdx.x & 63;
  int stride = gridDim.x * 4;
  for (int row = row0; row < n; row += stride) {
    const float* p = in + (size_t)row * HID;
    float a = p[lane], c = p[lane + 64];
    float s = wave_allreduce_sum(a + c);
    float s2 = wave_allreduce_sum(a * a + c * c);
    float mean = s * (1.f / 128.f);
    float var = s2 * (1.f / 128.f) - mean * mean;
    float rs = rsqrtf(var + 1e-5f);
    u16* o = out + (size_t)row * HID;
    o[lane] = f2bf((a - mean) * rs * w[lane] + b[lane]);
    o[lane + 64] = f2bf((c - mean) * rs * w[lane + 64] + b[lane + 64]);
  }
}

// ---------- weight conversion + cnt zero-fill ----------
__global__ __launch_bounds__(256) void convert_weights(
    const float* __restrict__ Wq, const float* __restrict__ Wk,
    const float* __restrict__ Wv, const float* __restrict__ Ws,
    const float* __restrict__ W1, const float* __restrict__ W2,
    const float* __restrict__ We, u16* __restrict__ WqkvsT,
    u16* __restrict__ W1T, u16* __restrict__ W2T, u16* __restrict__ WbdT,
    int* __restrict__ cnt, int Nn) {
  int idx = blockIdx.x * 256 + threadIdx.x;
  if (idx < 65536) {
    int m = idx >> 7, k = idx & 127;
    const float* Wm = m < 128 ? Wq : m < 256 ? Wk : m < 384 ? Wv : Ws;
    WqkvsT[idx] = f2bf(Wm[k * 128 + (m & 127)]);
  } else if (idx < 131072) {
    int j = idx - 65536;
    int m = j >> 7, k = j & 127;
    W1T[j] = f2bf(W1[k * 512 + m]);
  } else if (idx < 196608) {
    int j = idx - 131072;
    int m = j >> 9, k = j & 511;
    W2T[j] = f2bf(W2[k * 128 + m]);
  } else if (idx < 229376) {
    int j = idx - 196608;  // WbdT [128][256]
    int m = j >> 8, c = j & 255;
    WbdT[j] = ((c >> 5) == (m >> 4)) ? f2bf(We[(c & 31) * 128 + m]) : (u16)0;
  } else if (idx < 229376 + Nn) {
    cnt[idx - 229376] = 0;
  }
}

// ---------- bf16 MFMA GEMM: tile 128x128, 4 waves, 2-phase double-buffered LDS ----------
#define GSTAGE(buf, kc)                                                        \
  {                                                                            \
    _Pragma("unroll") for (int i = 0; i < 2; i++) {                            \
      int idx = i * 256 + t;                                                   \
      int row = idx >> 2, c4 = idx & 3;                                        \
      __builtin_amdgcn_global_load_lds(                                        \
          (const __attribute__((address_space(1))) u32*)(A + (size_t)(r0 + row) * K + (kc) + c4 * 8), \
          (__attribute__((address_space(3))) u32*)&As[buf][idx * 8], 16, 0, 0);\
      __builtin_amdgcn_global_load_lds(                                        \
          (const __attribute__((address_space(1))) u32*)(Bt + (size_t)(c0 + row) * K + (kc) + c4 * 8), \
          (__attribute__((address_space(3))) u32*)&Bs[buf][idx * 8], 16, 0, 0);\
    }                                                                          \
  }

#define GEMM_CORE                                                              \
  constexpr int NT = K / 32;                                                   \
  GSTAGE(0, 0)                                                                 \
  __syncthreads();                                                             \
  _Pragma("unroll") for (int tt = 0; tt < NT; tt++) {                          \
    if (tt + 1 < NT) GSTAGE((tt + 1) & 1, (tt + 1) * 32)                       \
    bf16x8 a0 = *(const bf16x8*)&As[tt & 1][(w * 32 + sr) * 32 + g * 8];       \
    bf16x8 a1 = *(const bf16x8*)&As[tt & 1][(w * 32 + 16 + sr) * 32 + g * 8];  \
    _Pragma("unroll") for (int nn = 0; nn < 8; nn++) {                         \
      bf16x8 b = *(const bf16x8*)&Bs[tt & 1][(nn * 16 + sr) * 32 + g * 8];     \
      acc[0][nn] = __builtin_amdgcn_mfma_f32_16x16x32_bf16(a0, b, acc[0][nn], 0, 0, 0); \
      acc[1][nn] = __builtin_amdgcn_mfma_f32_16x16x32_bf16(a1, b, acc[1][nn], 0, 0, 0); \
    }                                                                          \
    __syncthreads();                                                           \
  }

// EPI: 0 = QKVS (y0->pq packed, y1/y2->pkv packed, y3->skip f32)
//      1 = GELU->bf16 ; 2 = +bias+addsrc->f32
template <int EPI, int K>
__global__ __launch_bounds__(256) void gemm_bf16(
    const u16* __restrict__ A, const u16* __restrict__ Bt, int n,
    const float* __restrict__ bias0, const float* __restrict__ bias1,
    const float* __restrict__ bias2, const float* __restrict__ bias3,
    float* __restrict__ of0, u32* __restrict__ opq, u32* __restrict__ pkv,
    u16* __restrict__ ob1, const float* __restrict__ addsrc) {
  __shared__ u16 As[2][128 * 32];
  __shared__ u16 Bs[2][128 * 32];
  int t = threadIdx.x;
  int w = t >> 6, lane = t & 63;
  int g = lane >> 4, sr = lane & 15;
  int r0 = blockIdx.x * 128;
  int c0 = blockIdx.y * 128;
  f32x4 acc[2][8];
#pragma unroll
  for (int m = 0; m < 2; m++)
#pragma unroll
    for (int nn = 0; nn < 8; nn++) acc[m][nn] = {0.f, 0.f, 0.f, 0.f};

  GEMM_CORE

  if (EPI == 0 && blockIdx.y == 0) {  // Q packed
#pragma unroll
    for (int m = 0; m < 2; m++)
#pragma unroll
      for (int nn = 0; nn < 4; nn++)
#pragma unroll
        for (int j = 0; j < 4; j++) {
          int row = r0 + w * 32 + m * 16 + g * 4 + j;
          if (row < n) {
            int cj = nn * 16 + sr;
            opq[((size_t)row << 6) + cj] =
                pack2(acc[m][nn][j] + bias0[cj], acc[m][nn + 4][j] + bias0[cj + 64]);
          }
        }
    return;
  }
  if (EPI == 0 && (blockIdx.y == 1 || blockIdx.y == 2)) {  // K/V packed
    const float* bp = blockIdx.y == 1 ? bias1 : bias2;
    int which = blockIdx.y - 1;
#pragma unroll
    for (int m = 0; m < 2; m++)
#pragma unroll
      for (int nn = 0; nn < 4; nn++)
#pragma unroll
        for (int j = 0; j < 4; j++) {
          int row = r0 + w * 32 + m * 16 + g * 4 + j;
          if (row < n) {
            int cj = nn * 16 + sr;
            pkv[((size_t)row << 7) + (cj << 1) + which] =
                pack2(acc[m][nn][j] + bp[cj], acc[m][nn + 4][j] + bp[cj + 64]);
          }
        }
    return;
  }
#pragma unroll
  for (int m = 0; m < 2; m++)
#pragma unroll
    for (int nn = 0; nn < 8; nn++)
#pragma unroll
      for (int j = 0; j < 4; j++) {
        int row = r0 + w * 32 + m * 16 + g * 4 + j;
        if (row < n) {
          int cj = nn * 16 + sr;
          float val = acc[m][nn][j];
          if (EPI == 0) {  // y==3: skip, f32
            of0[(size_t)row * HID + cj] = val + bias3[cj];
          } else if (EPI == 1) {
            int cjg = blockIdx.y * 128 + cj;
            float v2 = val + bias0[cjg];
            v2 = 0.5f * v2 * (1.f + erff(v2 * 0.70710678118f));
            ob1[(size_t)row * 512 + cjg] = f2bf(v2);
          } else {  // EPI == 2
            of0[(size_t)row * HID + cj] = val + bias0[cj] + addsrc[(size_t)row * HID + cj];
          }
        }
      }
}

// ---------- bd-GEMM (K=256) fused with finalize + LN2 ----------
__global__ __launch_bounds__(256) void gemm_bd_fin(
    const u16* __restrict__ A, const u16* __restrict__ Bt, int n,
    const float* __restrict__ x, const float* __restrict__ msg,
    const float* __restrict__ lbuf, const float* __restrict__ be,
    const float* __restrict__ lnw, const float* __restrict__ lnb,
    float* __restrict__ skipx1, u16* __restrict__ h2) {
  __shared__ u16 As[2][128 * 32];
  __shared__ u16 Bs[2][128 * 32];
  constexpr int K = 256;
  int t = threadIdx.x;
  int w = t >> 6, lane = t & 63;
  int g = lane >> 4, sr = lane & 15;
  int r0 = blockIdx.x * 128;
  int c0 = 0;
  f32x4 acc[2][8];
#pragma unroll
  for (int m = 0; m < 2; m++)
#pragma unroll
    for (int nn = 0; nn < 8; nn++) acc[m][nn] = {0.f, 0.f, 0.f, 0.f};

  GEMM_CORE

  float becol[8], wcol[8], bcol[8];
#pragma unroll
  for (int nn = 0; nn < 8; nn++) {
    int c = nn * 16 + sr;
    becol[nn] = be[c];
    wcol[nn] = lnw[c];
    bcol[nn] = lnb[c];
  }
#pragma unroll
  for (int m = 0; m < 2; m++)
#pragma unroll
    for (int j = 0; j < 4; j++) {
      int row = r0 + w * 32 + m * 16 + g * 4 + j;
      if (row < n) {
        const float* xr = x + (size_t)row * HID;
        const float* mr = msg + (size_t)row * HID;
        float* sxr = skipx1 + (size_t)row * HID;
        f32x4 L0 = *(const f32x4*)(lbuf + (size_t)row * 8);
        f32x4 L1 = *(const f32x4*)(lbuf + (size_t)row * 8 + 4);
        float tv[8];
        float s = 0.f, s2 = 0.f;
#pragma unroll
        for (int nn = 0; nn < 8; nn++) {
          int c = nn * 16 + sr;
          float linv = nn < 4 ? L0[nn] : L1[nn - 4];
          float t1 = xr[c] + (mr[c] + acc[m][nn][j]) * linv + becol[nn] + sxr[c];
          tv[nn] = t1;
          s += t1;
          s2 = fmaf(t1, t1, s2);
        }
        s = grp16_sum(s);
        s2 = grp16_sum(s2);
        float mean = s * (1.f / 128.f);
        float var = s2 * (1.f / 128.f) - mean * mean;
        float rs = rsqrtf(var + 1e-5f);
        u16* h2r = h2 + (size_t)row * HID;
#pragma unroll
        for (int nn = 0; nn < 8; nn++) {
          int c = nn * 16 + sr;
          sxr[c] = tv[nn];
          h2r[c] = f2bf((tv[nn] - mean) * rs * wcol[nn] + bcol[nn]);
        }
      }
    }
}

// ---------- counting sort by dst ----------
__global__ __launch_bounds__(256) void hist_kernel(const int* __restrict__ dstp,
                                                   int* __restrict__ cnt, int E) {
  int i = blockIdx.x * blockDim.x + threadIdx.x;
  int stride = gridDim.x * blockDim.x;
  for (; i < E; i += stride) atomicAdd(&cnt[dstp[i]], 1);
}

__global__ __launch_bounds__(256) void scan_partial(const int* __restrict__ cnt,
                                                    int* __restrict__ bs, int N) {
  __shared__ int sd[256];
  int idx = blockIdx.x * 256 + threadIdx.x;
  sd[threadIdx.x] = (idx < N) ? cnt[idx] : 0;
  __syncthreads();
  for (int s = 128; s > 0; s >>= 1) {
    if (threadIdx.x < s) sd[threadIdx.x] += sd[threadIdx.x + s];
    __syncthreads();
  }
  if (threadIdx.x == 0) bs[blockIdx.x] = sd[0];
}

__global__ __launch_bounds__(256) void scan_bs(const int* __restrict__ bs,
                                               int* __restrict__ bs2, int nb) {
  __shared__ int sd[256];
  int t = threadIdx.x;
  int v = (t < nb) ? bs[t] : 0;
  sd[t] = v;
  __syncthreads();
  for (int s = 1; s < 256; s <<= 1) {
    int add = (t >= s) ? sd[t - s] : 0;
    __syncthreads();
    sd[t] += add;
    __syncthreads();
  }
  bs2[t] = sd[t] - v;  // exclusive
}

__global__ __launch_bounds__(256) void scan_final(const int* __restrict__ cnt,
                                                  const int* __restrict__ bs2,
                                                  int* __restrict__ offs,
                                                  int* __restrict__ woff, int N) {
  __shared__ int sd[256];
  int t = threadIdx.x;
  int idx = blockIdx.x * 256 + t;
  int v = (idx < N) ? cnt[idx] : 0;
  sd[t] = v;
  __syncthreads();
  for (int s = 1; s < 256; s <<= 1) {
    int add = (t >= s) ? sd[t - s] : 0;
    __syncthreads();
    sd[t] += add;
    __syncthreads();
  }
  if (idx < N) {
    int ex = sd[t] - v + bs2[blockIdx.x];
    offs[idx] = ex;
    woff[idx] = ex;
  }
}

__global__ __launch_bounds__(256) void scatter_kernel(const int* __restrict__ ei,
                                                      int* __restrict__ woff,
                                                      int2* __restrict__ sorted,
                                                      int E) {
  int i = blockIdx.x * blockDim.x + threadIdx.x;
  int stride = gridDim.x * blockDim.x;
  for (; i < E; i += stride) {
    int src = ei[i];
    int dst = ei[E + i];
    int pos = atomicAdd(&woff[dst], 1);
    sorted[pos] = make_int2(src, i);
  }
}

// ---------- qWe precompute (grid-stride; LDS staged once per block) ----------
__global__ __launch_bounds__(256) void qwe_kernel(const u32* __restrict__ pq,
                                                  const float* __restrict__ We,
                                                  const float* __restrict__ be,
                                                  u32* __restrict__ qweb,
                                                  float* __restrict__ qbe, int Nn) {
  __shared__ float sWe[32][129];
  __shared__ float sbe[128];
  int t = threadIdx.x;
  for (int i = t; i < 32 * 128; i += 256) sWe[i >> 7][i & 127] = We[i];
  if (t < 128) sbe[t] = be[t];
  __syncthreads();
  int lane = t & 63, w = t >> 6;
  int g = lane >> 4, sr = lane & 15;
  int base = lane & 48;
  int stride = gridDim.x * 4;
  for (int node = blockIdx.x * 4 + w; node < Nn; node += stride) {
    u32 pw = pq[(size_t)node * 64 + lane];
    float q0 = bflo(pw), q1 = bfhi(pw);
    float o00 = 0.f, o01 = 0.f, o10 = 0.f, o11 = 0.f;
#pragma unroll
    for (int d0 = 0; d0 < 16; d0++) {
      float qa = __shfl(q0, base + d0);
      float qb = __shfl(q1, base + d0);
      int col = base + d0;
      o00 += qa * sWe[2 * sr][col];
      o01 += qa * sWe[2 * sr + 1][col];
      o10 += qb * sWe[2 * sr][64 + col];
      o11 += qb * sWe[2 * sr + 1][64 + col];
    }
    qweb[(size_t)node * 128 + g * 16 + sr] = pack2(o00 * SC, o01 * SC);
    qweb[(size_t)node * 128 + 64 + g * 16 + sr] = pack2(o10 * SC, o11 * SC);
    float t0 = grp16_sum(q0 * sbe[lane]);
    float t1 = grp16_sum(q1 * sbe[lane + 64]);
    if (sr == 0) {
      qbe[node * 8 + g] = t0 * SC;
      qbe[node * 8 + 4 + g] = t1 * SC;
    }
  }
}

// ---------- fused edge attention ----------
// 4 rotating register buffer sets, 16-edge prologue, issue c+16..23 while computing c.
#define ISSUE4(P, base_)                                                       \
  {                                                                            \
    _Pragma("unroll") for (int jj = 0; jj < 4; jj++) {                         \
      int sj = min(base_ + jj, segn - 1);                                      \
      int sxx = __builtin_amdgcn_readlane(seRx, sj);                           \
      int syy = __builtin_amdgcn_readlane(seRy, sj);                           \
      P##kv[jj] = *(const u32x2*)(pkv + ((size_t)sxx << 7) + (lane << 1));     \
      P##ea[jj] = *(const float2*)(eaf + ((size_t)syy << 5) + 2 * sr);         \
    }                                                                          \
  }

#define COMP4(P, base_)                                                        \
  {                                                                            \
    _Pragma("unroll") for (int jj = 0; jj < 4; jj++) {                         \
      u32 kx = P##kv[jj].x, ky = P##kv[jj].y;                                  \
      float ex = P##ea[jj].x, ey = P##ea[jj].y;                                \
      float k0 = bflo(kx), k1 = bfhi(kx);                                      \
      float v0f = bflo(ky), v1f = bfhi(ky);                                    \
      float p0 = fmaf(q0C, k0, fmaf(qw0x, ex, qw0y * ey));                     \
      float p1 = fmaf(q1C, k1, fmaf(qw1x, ex, qw1y * ey));                     \
      p0 = grp16_sum(p0) + qb0C;                                               \
      p1 = grp16_sum(p1) + qb1C;                                               \
      bool val_ = (base_ + jj) < segn;                                         \
      float w1 = val_ ? __builtin_amdgcn_exp2f(p0) : 0.f;                      \
      float w2 = val_ ? __builtin_amdgcn_exp2f(p1) : 0.f;                      \
      l1 += w1;                                                                \
      l2 += w2;                                                                \
      a0 = fmaf(w1, v0f, a0);                                                  \
      a1 = fmaf(w2, v1f, a1);                                                  \
      wa00 = fmaf(w1, ex, wa00);                                               \
      wa01 = fmaf(w1, ey, wa01);                                               \
      wa10 = fmaf(w2, ex, wa10);                                               \
      wa11 = fmaf(w2, ey, wa11);                                               \
    }                                                                          \
  }

__global__ __launch_bounds__(256) void fused_edge(
    const int* __restrict__ offs, const int* __restrict__ cnt,
    const int2* __restrict__ sorted, const float* __restrict__ eaf,
    const float* __restrict__ be, const u32* __restrict__ pq,
    const u32* __restrict__ pkv, const u32* __restrict__ qweb,
    const float* __restrict__ qbe, float* __restrict__ msg,
    u32* __restrict__ weab, float* __restrict__ lbuf, int Nn, int Etot) {
  int lane = threadIdx.x & 63;
  int w = threadIdx.x >> 6;
  int g = lane >> 4, sr = lane & 15;
  int wid = blockIdx.x * 4 + w;
  int nw = gridDim.x * 4;
  int per = (Nn + nw - 1) / nw;
  int n0 = wid * per;
  int n1 = min(Nn, n0 + per);
  if (n0 >= n1) return;
  int nn = n1 - n0;

  float be0 = be[lane], be1 = be[lane + 64];

  int ml = min(lane, nn - 1);
  int myBeg = offs[n0 + ml];
  int myCnt = cnt[n0 + ml];

  // prefetch node 0 state
  int beg = __builtin_amdgcn_readlane(myBeg, 0);
  int num = __builtin_amdgcn_readlane(myCnt, 0);
  int2 se2 = sorted[min(beg + min(lane, max(num - 1, 0)), Etot - 1)];
  int seCx = se2.x, seCy = se2.y;
  u32 pqC = pq[(size_t)n0 * 64 + lane];
  u32 qwb0C = qweb[(size_t)n0 * 128 + g * 16 + sr];
  u32 qwb1C = qweb[(size_t)n0 * 128 + 64 + g * 16 + sr];
  float qb0C = qbe[(size_t)n0 * 8 + g], qb1C = qbe[(size_t)n0 * 8 + 4 + g];

  for (int ni = 0; ni < nn; ni++) {
    int node = n0 + ni;
    // next-node prefetch (independent of current compute)
    int begX = 0, numX = 0, seXx = 0, seXy = 0;
    u32 pqX = 0, qwb0X = 0, qwb1X = 0;
    float qb0X = 0.f, qb1X = 0.f;
    if (ni + 1 < nn) {
      begX = __builtin_amdgcn_readlane(myBeg, ni + 1);
      numX = __builtin_amdgcn_readlane(myCnt, ni + 1);
      int2 sx = sorted[min(begX + min(lane, max(numX - 1, 0)), Etot - 1)];
      seXx = sx.x;
      seXy = sx.y;
      pqX = pq[(size_t)(node + 1) * 64 + lane];
      qwb0X = qweb[(size_t)(node + 1) * 128 + g * 16 + sr];
      qwb1X = qweb[(size_t)(node + 1) * 128 + 64 + g * 16 + sr];
      qb0X = qbe[(size_t)(node + 1) * 8 + g];
      qb1X = qbe[(size_t)(node + 1) * 8 + 4 + g];
    }
    float q0C = bflo(pqC) * SC, q1C = bfhi(pqC) * SC;
    float qw0x = bflo(qwb0C), qw0y = bfhi(qwb0C);
    float qw1x = bflo(qwb1C), qw1y = bfhi(qwb1C);
    float l1 = 0.f, l2 = 0.f, a0 = 0.f, a1 = 0.f;
    float wa00 = 0.f, wa01 = 0.f, wa10 = 0.f, wa11 = 0.f;
    if (num > 0) {
      int cb = 0;
      int seRx = seCx, seRy = seCy;
      while (true) {
        int segn = min(num - cb, 64);
        u32x2 Akv[4], Bkv[4], Ckv[4], Dkv[4];
        float2 Aea[4], Bea[4], Cea[4], Dea[4];
        ISSUE4(A, 0)
        ISSUE4(B, 4)
        ISSUE4(C, 8)
        ISSUE4(D, 12)
        int c = 0;
        while (c < segn) {
          COMP4(A, c)
          ISSUE4(A, c + 16)
          COMP4(B, c + 4)
          ISSUE4(B, c + 20)
          c += 8;
          if (c >= segn) break;
          COMP4(C, c)
          ISSUE4(C, c + 16)
          COMP4(D, c + 4)
          ISSUE4(D, c + 20)
          c += 8;
        }
        cb += 64;
        if (cb >= num) break;
        int rem = num - cb;
        int2 sn = sorted[min(beg + cb + min(lane, rem - 1), Etot - 1)];
        seRx = sn.x;
        seRy = sn.y;
      }
    }
    size_t ob = (size_t)node * HID + lane;
    if (num > 0) {
      msg[ob] = a0;
      msg[ob + 64] = a1;
    } else {  // empty segment: bd_fin adds be -> cancel it
      msg[ob] = -be0;
      msg[ob + 64] = -be1;
    }
    weab[(size_t)node * 128 + g * 16 + sr] = pack2(wa00, wa01);
    weab[(size_t)node * 128 + 64 + g * 16 + sr] = pack2(wa10, wa11);
    if (sr == 0) {  // store reciprocals (bd_fin multiplies)
      lbuf[(size_t)node * 8 + g] = (num > 0) ? 1.f / (l1 + 1e-30f) : 1.f;
      lbuf[(size_t)node * 8 + 4 + g] = (num > 0) ? 1.f / (l2 + 1e-30f) : 1.f;
    }
    beg = begX;
    num = numX;
    seCx = seXx;
    seCy = seXy;
    pqC = pqX;
    qwb0C = qwb0X;
    qwb1C = qwb1X;
    qb0C = qb0X;
    qb1C = qb1X;
  }
}

extern "C" void kernel_launch(void* const* d_in, const int* in_sizes, int n_in,
                              void* d_out, int out_size, void* d_ws, size_t ws_size,
                              hipStream_t stream) {
  const float* x = (const float*)d_in[0];
  const int* ei = (const int*)d_in[1];
  const float* ea = (const float*)d_in[2];
  const float* Wq = (const float*)d_in[3];
  const float* bq = (const float*)d_in[4];
  const float* Wk = (const float*)d_in[5];
  const float* bk = (const float*)d_in[6];
  const float* Wv = (const float*)d_in[7];
  const float* bv = (const float*)d_in[8];
  const float* We = (const float*)d_in[9];
  const float* be = (const float*)d_in[10];
  const float* Wskip = (const float*)d_in[11];
  const float* bskip = (const float*)d_in[12];
  const float* ln1w = (const float*)d_in[13];
  const float* ln1b = (const float*)d_in[14];
  const float* W1 = (const float*)d_in[15];
  const float* b1p = (const float*)d_in[16];
  const float* W2 = (const float*)d_in[17];
  const float* b2p = (const float*)d_in[18];
  const float* ln2w = (const float*)d_in[19];
  const float* ln2b = (const float*)d_in[20];

  int N = in_sizes[0] / HID;
  int E = in_sizes[1] / 2;
  size_t nf = (size_t)N * HID;

  float* ws = (float*)d_ws;
  size_t off = 0;
  u16* h_bf = (u16*)(ws + off); off += nf / 2;
  u32* pq = (u32*)(ws + off); off += nf / 2;   // [node][64] packed q
  u32* pkv = (u32*)(ws + off); off += nf;      // [node][64]{kword,vword}
  float* skipx1 = ws + off; off += nf;         // skip, overwritten with x1
  float* msg = ws + off; off += nf;            // + weab below: aliased by tbf in FFN
  u32* weab = (u32*)(ws + off); off += nf;     // [node][128] packed bf16 pairs
  float* lbuf = ws + off; off += (size_t)N * 8;  // reciprocals
  u32* qweb = (u32*)(ws + off); off += nf;     // [node][128] packed bf16 qWe
  float* qbe = ws + off; off += (size_t)N * 8;
  int2* sorted = (int2*)(ws + off); off += (size_t)E * 2;  // {src, eid}
  int* cnt = (int*)(ws + off); off += N;
  int* offs = (int*)(ws + off); off += N;
  int* woff = (int*)(ws + off); off += N;
  int* bs = (int*)(ws + off); off += 256;
  int* bs2 = (int*)(ws + off); off += 256;
  u16* WqkvsT = (u16*)(ws + off); off += 32768;
  u16* W1T = (u16*)(ws + off); off += 32768;
  u16* W2T = (u16*)(ws + off); off += 32768;
  u16* WbdT = (u16*)(ws + off); off += 16384;
  u16* h2bf = h_bf;      // h_bf dead after QKVS GEMM
  u16* tbf = (u16*)msg;  // FFN intermediate aliases msg+weab (dead after bd_fin)

  convert_weights<<<1092, 256, 0, stream>>>(Wq, Wk, Wv, Wskip, W1, W2, We,
                                            WqkvsT, W1T, W2T, WbdT, cnt, N);

  int ln_blocks = (N + 3) / 4;
  ln_kernel<<<ln_blocks, 256, 0, stream>>>(x, h_bf, ln1w, ln1b, N);

  dim3 gq((N + 127) / 128, 4);
  gemm_bf16<0, 128><<<gq, 256, 0, stream>>>(h_bf, WqkvsT, N, bq, bk, bv, bskip,
                                            skipx1, pq, pkv, nullptr, nullptr);

  int nb = (N + 255) / 256;
  hist_kernel<<<1024, 256, 0, stream>>>(ei + E, cnt, E);
  scan_partial<<<nb, 256, 0, stream>>>(cnt, bs, N);
  scan_bs<<<1, 256, 0, stream>>>(bs, bs2, nb);
  scan_final<<<nb, 256, 0, stream>>>(cnt, bs2, offs, woff, N);
  scatter_kernel<<<1024, 256, 0, stream>>>(ei, woff, sorted, E);

  qwe_kernel<<<1024, 256, 0, stream>>>(pq, We, be, qweb, qbe, N);

  int fe_blocks = (N + 7) / 8;  // 4 waves/block, 2 nodes/wave
  fused_edge<<<fe_blocks, 256, 0, stream>>>(offs, cnt, sorted, ea, be, pq, pkv,
                                            qweb, qbe, msg, weab, lbuf, N, E);

  // bd-GEMM + finalize + LN2 fused
  dim3 ge((N + 127) / 128, 1);
  gemm_bd_fin<<<ge, 256, 0, stream>>>((const u16*)weab, WbdT, N, x, msg, lbuf,
                                      be, ln2w, ln2b, skipx1, h2bf);

  dim3 gf1((N + 127) / 128, 4);
  gemm_bf16<1, 128><<<gf1, 256, 0, stream>>>(h2bf, W1T, N, b1p, nullptr, nullptr,
                                             nullptr, nullptr, nullptr, nullptr,
                                             tbf, nullptr);
  dim3 gf2((N + 127) / 128, 1);
  gemm_bf16<2, 512><<<gf2, 256, 0, stream>>>(tbf, W2T, N, b2p, nullptr, nullptr,
                                             nullptr, (float*)d_out, nullptr,
                                             nullptr, nullptr, skipx1);
}

// Round 11
// 429.161 us; speedup vs baseline: 1.0836x; 1.0836x over previous
//
#include <hip/hip_runtime.h>
#include <math.h>

#define HID 128
#define EDGE_D 32
#define SC 0.36067376f  // 0.25 * log2(e)

typedef unsigned short u16;
typedef unsigned int u32;
typedef __bf16 bf16x8 __attribute__((ext_vector_type(8)));
typedef float f32x4 __attribute__((ext_vector_type(4)));
typedef u32 u32x4 __attribute__((ext_vector_type(4)));
typedef u32 u32x2 __attribute__((ext_vector_type(2)));

static __device__ __forceinline__ u16 f2bf(float f) {
  u32 u = __float_as_uint(f);
  u += 0x7fffu + ((u >> 16) & 1u);
  return (u16)(u >> 16);
}
static __device__ __forceinline__ u32 pack2(float a, float b) {
  return (u32)f2bf(a) | ((u32)f2bf(b) << 16);
}
static __device__ __forceinline__ float bflo(u32 w) { return __uint_as_float(w << 16); }
static __device__ __forceinline__ float bfhi(u32 w) { return __uint_as_float(w & 0xffff0000u); }
// all-lanes sum within each 16-lane row via DPP row rotates (pure VALU)
static __device__ __forceinline__ float grp16_sum(float x) {
  x += __int_as_float(__builtin_amdgcn_mov_dpp(__float_as_int(x), 0x128, 0xf, 0xf, true));
  x += __int_as_float(__builtin_amdgcn_mov_dpp(__float_as_int(x), 0x124, 0xf, 0xf, true));
  x += __int_as_float(__builtin_amdgcn_mov_dpp(__float_as_int(x), 0x122, 0xf, 0xf, true));
  x += __int_as_float(__builtin_amdgcn_mov_dpp(__float_as_int(x), 0x121, 0xf, 0xf, true));
  return x;
}
static __device__ __forceinline__ float wave_allreduce_sum(float v) {
#pragma unroll
  for (int off = 32; off > 0; off >>= 1) v += __shfl_xor(v, off);
  return v;
}

// ---------- LayerNorm: out_bf16 = LN(in) ----------
__global__ __launch_bounds__(256) void ln_kernel(const float* __restrict__ in,
                                                 u16* __restrict__ out,
                                                 const float* __restrict__ w,
                                                 const float* __restrict__ b, int n) {
  int row0 = blockIdx.x * 4 + (threadIdx.x >> 6);
  int lane = threadIdx.x & 63;
  int stride = gridDim.x * 4;
  for (int row = row0; row < n; row += stride) {
    const float* p = in + (size_t)row * HID;
    float a = p[lane], c = p[lane + 64];
    float s = wave_allreduce_sum(a + c);
    float s2 = wave_allreduce_sum(a * a + c * c);
    float mean = s * (1.f / 128.f);
    float var = s2 * (1.f / 128.f) - mean * mean;
    float rs = rsqrtf(var + 1e-5f);
    u16* o = out + (size_t)row * HID;
    o[lane] = f2bf((a - mean) * rs * w[lane] + b[lane]);
    o[lane + 64] = f2bf((c - mean) * rs * w[lane + 64] + b[lane + 64]);
  }
}

// ---------- weight conversion + cnt zero-fill ----------
__global__ __launch_bounds__(256) void convert_weights(
    const float* __restrict__ Wq, const float* __restrict__ Wk,
    const float* __restrict__ Wv, const float* __restrict__ Ws,
    const float* __restrict__ W1, const float* __restrict__ W2,
    const float* __restrict__ We, u16* __restrict__ WqkvsT,
    u16* __restrict__ W1T, u16* __restrict__ W2T, u16* __restrict__ WbdT,
    int* __restrict__ cnt, int Nn) {
  int idx = blockIdx.x * 256 + threadIdx.x;
  if (idx < 65536) {
    int m = idx >> 7, k = idx & 127;
    const float* Wm = m < 128 ? Wq : m < 256 ? Wk : m < 384 ? Wv : Ws;
    WqkvsT[idx] = f2bf(Wm[k * 128 + (m & 127)]);
  } else if (idx < 131072) {
    int j = idx - 65536;
    int m = j >> 7, k = j & 127;
    W1T[j] = f2bf(W1[k * 512 + m]);
  } else if (idx < 196608) {
    int j = idx - 131072;
    int m = j >> 9, k = j & 511;
    W2T[j] = f2bf(W2[k * 128 + m]);
  } else if (idx < 229376) {
    int j = idx - 196608;  // WbdT [128][256]
    int m = j >> 8, c = j & 255;
    WbdT[j] = ((c >> 5) == (m >> 4)) ? f2bf(We[(c & 31) * 128 + m]) : (u16)0;
  } else if (idx < 229376 + Nn) {
    cnt[idx - 229376] = 0;
  }
}

// ---------- bf16 MFMA GEMM: tile 128x128, 4 waves, 2-phase double-buffered LDS ----------
#define GSTAGE(buf, kc)                                                        \
  {                                                                            \
    _Pragma("unroll") for (int i = 0; i < 2; i++) {                            \
      int idx = i * 256 + t;                                                   \
      int row = idx >> 2, c4 = idx & 3;                                        \
      __builtin_amdgcn_global_load_lds(                                        \
          (const __attribute__((address_space(1))) u32*)(A + (size_t)(r0 + row) * K + (kc) + c4 * 8), \
          (__attribute__((address_space(3))) u32*)&As[buf][idx * 8], 16, 0, 0);\
      __builtin_amdgcn_global_load_lds(                                        \
          (const __attribute__((address_space(1))) u32*)(Bt + (size_t)(c0 + row) * K + (kc) + c4 * 8), \
          (__attribute__((address_space(3))) u32*)&Bs[buf][idx * 8], 16, 0, 0);\
    }                                                                          \
  }

#define GEMM_CORE                                                              \
  constexpr int NT = K / 32;                                                   \
  GSTAGE(0, 0)                                                                 \
  __syncthreads();                                                             \
  _Pragma("unroll") for (int tt = 0; tt < NT; tt++) {                          \
    if (tt + 1 < NT) GSTAGE((tt + 1) & 1, (tt + 1) * 32)                       \
    bf16x8 a0 = *(const bf16x8*)&As[tt & 1][(w * 32 + sr) * 32 + g * 8];       \
    bf16x8 a1 = *(const bf16x8*)&As[tt & 1][(w * 32 + 16 + sr) * 32 + g * 8];  \
    _Pragma("unroll") for (int nn = 0; nn < 8; nn++) {                         \
      bf16x8 b = *(const bf16x8*)&Bs[tt & 1][(nn * 16 + sr) * 32 + g * 8];     \
      acc[0][nn] = __builtin_amdgcn_mfma_f32_16x16x32_bf16(a0, b, acc[0][nn], 0, 0, 0); \
      acc[1][nn] = __builtin_amdgcn_mfma_f32_16x16x32_bf16(a1, b, acc[1][nn], 0, 0, 0); \
    }                                                                          \
    __syncthreads();                                                           \
  }

// EPI: 0 = QKV (y0->pq packed, y1/y2->pkv packed)
//      1 = GELU->bf16 ; 2 = +bias+addsrc->f32
template <int EPI, int K>
__global__ __launch_bounds__(256) void gemm_bf16(
    const u16* __restrict__ A, const u16* __restrict__ Bt, int n,
    const float* __restrict__ bias0, const float* __restrict__ bias1,
    const float* __restrict__ bias2,
    float* __restrict__ of0, u32* __restrict__ opq, u32* __restrict__ pkv,
    u16* __restrict__ ob1, const float* __restrict__ addsrc) {
  __shared__ u16 As[2][128 * 32];
  __shared__ u16 Bs[2][128 * 32];
  int t = threadIdx.x;
  int w = t >> 6, lane = t & 63;
  int g = lane >> 4, sr = lane & 15;
  int r0 = blockIdx.x * 128;
  int c0 = blockIdx.y * 128;
  f32x4 acc[2][8];
#pragma unroll
  for (int m = 0; m < 2; m++)
#pragma unroll
    for (int nn = 0; nn < 8; nn++) acc[m][nn] = {0.f, 0.f, 0.f, 0.f};

  GEMM_CORE

  if (EPI == 0 && blockIdx.y == 0) {  // Q packed
#pragma unroll
    for (int m = 0; m < 2; m++)
#pragma unroll
      for (int nn = 0; nn < 4; nn++)
#pragma unroll
        for (int j = 0; j < 4; j++) {
          int row = r0 + w * 32 + m * 16 + g * 4 + j;
          if (row < n) {
            int cj = nn * 16 + sr;
            opq[((size_t)row << 6) + cj] =
                pack2(acc[m][nn][j] + bias0[cj], acc[m][nn + 4][j] + bias0[cj + 64]);
          }
        }
    return;
  }
  if (EPI == 0) {  // y 1/2: K/V packed
    const float* bp = blockIdx.y == 1 ? bias1 : bias2;
    int which = blockIdx.y - 1;
#pragma unroll
    for (int m = 0; m < 2; m++)
#pragma unroll
      for (int nn = 0; nn < 4; nn++)
#pragma unroll
        for (int j = 0; j < 4; j++) {
          int row = r0 + w * 32 + m * 16 + g * 4 + j;
          if (row < n) {
            int cj = nn * 16 + sr;
            pkv[((size_t)row << 7) + (cj << 1) + which] =
                pack2(acc[m][nn][j] + bp[cj], acc[m][nn + 4][j] + bp[cj + 64]);
          }
        }
    return;
  }
#pragma unroll
  for (int m = 0; m < 2; m++)
#pragma unroll
    for (int nn = 0; nn < 8; nn++)
#pragma unroll
      for (int j = 0; j < 4; j++) {
        int row = r0 + w * 32 + m * 16 + g * 4 + j;
        if (row < n) {
          int cj = nn * 16 + sr;
          float val = acc[m][nn][j];
          if (EPI == 1) {
            int cjg = blockIdx.y * 128 + cj;
            float v2 = val + bias0[cjg];
            v2 = 0.5f * v2 * (1.f + erff(v2 * 0.70710678118f));
            ob1[(size_t)row * 512 + cjg] = f2bf(v2);
          } else {  // EPI == 2
            of0[(size_t)row * HID + cj] = val + bias0[cj] + addsrc[(size_t)row * HID + cj];
          }
        }
      }
}

// ---------- bd-GEMM (K=256 WEA' @ We_bd) + skip-GEMM (K=128 h @ WskipT) + finalize + LN2 ----
// x1 = x + msg + acc + be + bskip ; h2 = LN(x1). msg/WEA' already normalized by 1/l.
__global__ __launch_bounds__(256) void gemm_bd_fin(
    const u16* __restrict__ Aw, const u16* __restrict__ BtW,
    const u16* __restrict__ Ah, const u16* __restrict__ BtS, int n,
    const float* __restrict__ x, const float* __restrict__ msg,
    const float* __restrict__ be, const float* __restrict__ bskip,
    const float* __restrict__ lnw, const float* __restrict__ lnb,
    float* __restrict__ x1, u16* __restrict__ h2) {
  __shared__ u16 As[2][128 * 32];
  __shared__ u16 Bs[2][128 * 32];
  int t = threadIdx.x;
  int w = t >> 6, lane = t & 63;
  int g = lane >> 4, sr = lane & 15;
  int r0 = blockIdx.x * 128;
  int c0 = 0;
  f32x4 acc[2][8];
#pragma unroll
  for (int m = 0; m < 2; m++)
#pragma unroll
    for (int nn = 0; nn < 8; nn++) acc[m][nn] = {0.f, 0.f, 0.f, 0.f};

  {
    const u16* A = Aw;
    const u16* Bt = BtW;
    constexpr int K = 256;
    GEMM_CORE
  }
  {
    const u16* A = Ah;
    const u16* Bt = BtS;
    constexpr int K = 128;
    GEMM_CORE
  }

  float becol[8], wcol[8], bcol[8], bscol[8];
#pragma unroll
  for (int nn = 0; nn < 8; nn++) {
    int c = nn * 16 + sr;
    becol[nn] = be[c];
    bscol[nn] = bskip[c];
    wcol[nn] = lnw[c];
    bcol[nn] = lnb[c];
  }
#pragma unroll
  for (int m = 0; m < 2; m++)
#pragma unroll
    for (int j = 0; j < 4; j++) {
      int row = r0 + w * 32 + m * 16 + g * 4 + j;
      if (row < n) {
        const float* xr = x + (size_t)row * HID;
        const float* mr = msg + (size_t)row * HID;
        float* x1r = x1 + (size_t)row * HID;
        float tv[8];
        float s = 0.f, s2 = 0.f;
#pragma unroll
        for (int nn = 0; nn < 8; nn++) {
          int c = nn * 16 + sr;
          float t1 = xr[c] + mr[c] + acc[m][nn][j] + becol[nn] + bscol[nn];
          tv[nn] = t1;
          s += t1;
          s2 = fmaf(t1, t1, s2);
        }
        s = grp16_sum(s);
        s2 = grp16_sum(s2);
        float mean = s * (1.f / 128.f);
        float var = s2 * (1.f / 128.f) - mean * mean;
        float rs = rsqrtf(var + 1e-5f);
        u16* h2r = h2 + (size_t)row * HID;
#pragma unroll
        for (int nn = 0; nn < 8; nn++) {
          int c = nn * 16 + sr;
          x1r[c] = tv[nn];
          h2r[c] = f2bf((tv[nn] - mean) * rs * wcol[nn] + bcol[nn]);
        }
      }
    }
}

// ---------- counting sort by dst ----------
__global__ __launch_bounds__(256) void hist_kernel(const int* __restrict__ dstp,
                                                   int* __restrict__ cnt, int E) {
  int i = blockIdx.x * blockDim.x + threadIdx.x;
  int stride = gridDim.x * blockDim.x;
  for (; i < E; i += stride) atomicAdd(&cnt[dstp[i]], 1);
}

__global__ __launch_bounds__(256) void scan_partial(const int* __restrict__ cnt,
                                                    int* __restrict__ bs, int N) {
  __shared__ int sd[256];
  int idx = blockIdx.x * 256 + threadIdx.x;
  sd[threadIdx.x] = (idx < N) ? cnt[idx] : 0;
  __syncthreads();
  for (int s = 128; s > 0; s >>= 1) {
    if (threadIdx.x < s) sd[threadIdx.x] += sd[threadIdx.x + s];
    __syncthreads();
  }
  if (threadIdx.x == 0) bs[blockIdx.x] = sd[0];
}

__global__ __launch_bounds__(256) void scan_bs(const int* __restrict__ bs,
                                               int* __restrict__ bs2, int nb) {
  __shared__ int sd[256];
  int t = threadIdx.x;
  int v = (t < nb) ? bs[t] : 0;
  sd[t] = v;
  __syncthreads();
  for (int s = 1; s < 256; s <<= 1) {
    int add = (t >= s) ? sd[t - s] : 0;
    __syncthreads();
    sd[t] += add;
    __syncthreads();
  }
  bs2[t] = sd[t] - v;  // exclusive
}

__global__ __launch_bounds__(256) void scan_final(const int* __restrict__ cnt,
                                                  const int* __restrict__ bs2,
                                                  int* __restrict__ offs,
                                                  int* __restrict__ woff, int N) {
  __shared__ int sd[256];
  int t = threadIdx.x;
  int idx = blockIdx.x * 256 + t;
  int v = (idx < N) ? cnt[idx] : 0;
  sd[t] = v;
  __syncthreads();
  for (int s = 1; s < 256; s <<= 1) {
    int add = (t >= s) ? sd[t - s] : 0;
    __syncthreads();
    sd[t] += add;
    __syncthreads();
  }
  if (idx < N) {
    int ex = sd[t] - v + bs2[blockIdx.x];
    offs[idx] = ex;
    woff[idx] = ex;
  }
}

__global__ __launch_bounds__(256) void scatter_kernel(const int* __restrict__ ei,
                                                      int* __restrict__ woff,
                                                      int2* __restrict__ sorted,
                                                      int E) {
  int i = blockIdx.x * blockDim.x + threadIdx.x;
  int stride = gridDim.x * blockDim.x;
  for (; i < E; i += stride) {
    int src = ei[i];
    int dst = ei[E + i];
    int pos = atomicAdd(&woff[dst], 1);
    sorted[pos] = make_int2(src, i);
  }
}

// ---------- qWe precompute (grid-stride; LDS staged once per block) ----------
__global__ __launch_bounds__(256) void qwe_kernel(const u32* __restrict__ pq,
                                                  const float* __restrict__ We,
                                                  const float* __restrict__ be,
                                                  u32* __restrict__ qweb,
                                                  float* __restrict__ qbe, int Nn) {
  __shared__ float sWe[32][129];
  __shared__ float sbe[128];
  int t = threadIdx.x;
  for (int i = t; i < 32 * 128; i += 256) sWe[i >> 7][i & 127] = We[i];
  if (t < 128) sbe[t] = be[t];
  __syncthreads();
  int lane = t & 63, w = t >> 6;
  int g = lane >> 4, sr = lane & 15;
  int base = lane & 48;
  int stride = gridDim.x * 4;
  for (int node = blockIdx.x * 4 + w; node < Nn; node += stride) {
    u32 pw = pq[(size_t)node * 64 + lane];
    float q0 = bflo(pw), q1 = bfhi(pw);
    float o00 = 0.f, o01 = 0.f, o10 = 0.f, o11 = 0.f;
#pragma unroll
    for (int d0 = 0; d0 < 16; d0++) {
      float qa = __shfl(q0, base + d0);
      float qb = __shfl(q1, base + d0);
      int col = base + d0;
      o00 += qa * sWe[2 * sr][col];
      o01 += qa * sWe[2 * sr + 1][col];
      o10 += qb * sWe[2 * sr][64 + col];
      o11 += qb * sWe[2 * sr + 1][64 + col];
    }
    qweb[(size_t)node * 128 + g * 16 + sr] = pack2(o00 * SC, o01 * SC);
    qweb[(size_t)node * 128 + 64 + g * 16 + sr] = pack2(o10 * SC, o11 * SC);
    float t0 = grp16_sum(q0 * sbe[lane]);
    float t1 = grp16_sum(q1 * sbe[lane + 64]);
    if (sr == 0) {
      qbe[node * 8 + g] = t0 * SC;
      qbe[node * 8 + 4 + g] = t1 * SC;
    }
  }
}

// ---------- fused edge attention (2-deep pipeline, 4 nodes/wave) ----------
#define ISSUE4(P, base_)                                                       \
  {                                                                            \
    _Pragma("unroll") for (int jj = 0; jj < 4; jj++) {                         \
      int sj = min(base_ + jj, segn - 1);                                      \
      int sxx = __builtin_amdgcn_readlane(seRx, sj);                           \
      int syy = __builtin_amdgcn_readlane(seRy, sj);                           \
      P##kv[jj] = *(const u32x2*)(pkv + ((size_t)sxx << 7) + (lane << 1));     \
      P##ea[jj] = *(const float2*)(eaf + ((size_t)syy << 5) + 2 * sr);         \
    }                                                                          \
  }

#define COMP4(P, base_)                                                        \
  {                                                                            \
    _Pragma("unroll") for (int jj = 0; jj < 4; jj++) {                         \
      u32 kx = P##kv[jj].x, ky = P##kv[jj].y;                                  \
      float ex = P##ea[jj].x, ey = P##ea[jj].y;                                \
      float k0 = bflo(kx), k1 = bfhi(kx);                                      \
      float v0f = bflo(ky), v1f = bfhi(ky);                                    \
      float p0 = fmaf(q0C, k0, fmaf(qw0x, ex, qw0y * ey));                     \
      float p1 = fmaf(q1C, k1, fmaf(qw1x, ex, qw1y * ey));                     \
      p0 = grp16_sum(p0) + qb0C;                                               \
      p1 = grp16_sum(p1) + qb1C;                                               \
      bool val_ = (base_ + jj) < segn;                                         \
      float w1 = val_ ? __builtin_amdgcn_exp2f(p0) : 0.f;                      \
      float w2 = val_ ? __builtin_amdgcn_exp2f(p1) : 0.f;                      \
      l1 += w1;                                                                \
      l2 += w2;                                                                \
      a0 = fmaf(w1, v0f, a0);                                                  \
      a1 = fmaf(w2, v1f, a1);                                                  \
      wa00 = fmaf(w1, ex, wa00);                                               \
      wa01 = fmaf(w1, ey, wa01);                                               \
      wa10 = fmaf(w2, ex, wa10);                                               \
      wa11 = fmaf(w2, ey, wa11);                                               \
    }                                                                          \
  }

__global__ __launch_bounds__(256) void fused_edge(
    const int* __restrict__ offs, const int* __restrict__ cnt,
    const int2* __restrict__ sorted, const float* __restrict__ eaf,
    const float* __restrict__ be, const u32* __restrict__ pq,
    const u32* __restrict__ pkv, const u32* __restrict__ qweb,
    const float* __restrict__ qbe, float* __restrict__ msg,
    u32* __restrict__ weab, int Nn, int Etot) {
  int lane = threadIdx.x & 63;
  int w = threadIdx.x >> 6;
  int g = lane >> 4, sr = lane & 15;
  int wid = blockIdx.x * 4 + w;
  int nw = gridDim.x * 4;
  int per = (Nn + nw - 1) / nw;
  int n0 = wid * per;
  int n1 = min(Nn, n0 + per);
  if (n0 >= n1) return;
  int nn = n1 - n0;

  float be0 = be[lane], be1 = be[lane + 64];

  int ml = min(lane, nn - 1);
  int myBeg = offs[n0 + ml];
  int myCnt = cnt[n0 + ml];

  // prefetch node 0 state
  int beg = __builtin_amdgcn_readlane(myBeg, 0);
  int num = __builtin_amdgcn_readlane(myCnt, 0);
  int2 se2 = sorted[min(beg + min(lane, max(num - 1, 0)), Etot - 1)];
  int seCx = se2.x, seCy = se2.y;
  u32 pqC = pq[(size_t)n0 * 64 + lane];
  u32 qwb0C = qweb[(size_t)n0 * 128 + g * 16 + sr];
  u32 qwb1C = qweb[(size_t)n0 * 128 + 64 + g * 16 + sr];
  float qb0C = qbe[(size_t)n0 * 8 + g], qb1C = qbe[(size_t)n0 * 8 + 4 + g];

  for (int ni = 0; ni < nn; ni++) {
    int node = n0 + ni;
    // next-node prefetch (independent of current compute)
    int begX = 0, numX = 0, seXx = 0, seXy = 0;
    u32 pqX = 0, qwb0X = 0, qwb1X = 0;
    float qb0X = 0.f, qb1X = 0.f;
    if (ni + 1 < nn) {
      begX = __builtin_amdgcn_readlane(myBeg, ni + 1);
      numX = __builtin_amdgcn_readlane(myCnt, ni + 1);
      int2 sx = sorted[min(begX + min(lane, max(numX - 1, 0)), Etot - 1)];
      seXx = sx.x;
      seXy = sx.y;
      pqX = pq[(size_t)(node + 1) * 64 + lane];
      qwb0X = qweb[(size_t)(node + 1) * 128 + g * 16 + sr];
      qwb1X = qweb[(size_t)(node + 1) * 128 + 64 + g * 16 + sr];
      qb0X = qbe[(size_t)(node + 1) * 8 + g];
      qb1X = qbe[(size_t)(node + 1) * 8 + 4 + g];
    }
    float q0C = bflo(pqC) * SC, q1C = bfhi(pqC) * SC;
    float qw0x = bflo(qwb0C), qw0y = bfhi(qwb0C);
    float qw1x = bflo(qwb1C), qw1y = bfhi(qwb1C);
    float l1 = 0.f, l2 = 0.f, a0 = 0.f, a1 = 0.f;
    float wa00 = 0.f, wa01 = 0.f, wa10 = 0.f, wa11 = 0.f;
    if (num > 0) {
      int cb = 0;
      int seRx = seCx, seRy = seCy;
      while (true) {
        int segn = min(num - cb, 64);
        u32x2 Akv[4], Bkv[4];
        float2 Aea[4], Bea[4];
        ISSUE4(A, 0)
        for (int c = 0; c < segn; c += 8) {
          ISSUE4(B, c + 4)
          COMP4(A, c)
          ISSUE4(A, c + 8)
          COMP4(B, c + 4)
        }
        cb += 64;
        if (cb >= num) break;
        int rem = num - cb;
        int2 sn = sorted[min(beg + cb + min(lane, rem - 1), Etot - 1)];
        seRx = sn.x;
        seRy = sn.y;
      }
    }
    // epilogue: normalized outputs (fold 1/l here; bd_fin just adds)
    float inv1 = 1.f / (l1 + 1e-30f), inv2 = 1.f / (l2 + 1e-30f);
    size_t ob = (size_t)node * HID + lane;
    if (num > 0) {
      msg[ob] = a0 * inv1;
      msg[ob + 64] = a1 * inv2;
    } else {  // empty segment: bd_fin adds be -> cancel it
      msg[ob] = -be0;
      msg[ob + 64] = -be1;
    }
    weab[(size_t)node * 128 + g * 16 + sr] = pack2(wa00 * inv1, wa01 * inv1);
    weab[(size_t)node * 128 + 64 + g * 16 + sr] = pack2(wa10 * inv2, wa11 * inv2);
    beg = begX;
    num = numX;
    seCx = seXx;
    seCy = seXy;
    pqC = pqX;
    qwb0C = qwb0X;
    qwb1C = qwb1X;
    qb0C = qb0X;
    qb1C = qb1X;
  }
}

extern "C" void kernel_launch(void* const* d_in, const int* in_sizes, int n_in,
                              void* d_out, int out_size, void* d_ws, size_t ws_size,
                              hipStream_t stream) {
  const float* x = (const float*)d_in[0];
  const int* ei = (const int*)d_in[1];
  const float* ea = (const float*)d_in[2];
  const float* Wq = (const float*)d_in[3];
  const float* bq = (const float*)d_in[4];
  const float* Wk = (const float*)d_in[5];
  const float* bk = (const float*)d_in[6];
  const float* Wv = (const float*)d_in[7];
  const float* bv = (const float*)d_in[8];
  const float* We = (const float*)d_in[9];
  const float* be = (const float*)d_in[10];
  const float* Wskip = (const float*)d_in[11];
  const float* bskip = (const float*)d_in[12];
  const float* ln1w = (const float*)d_in[13];
  const float* ln1b = (const float*)d_in[14];
  const float* W1 = (const float*)d_in[15];
  const float* b1p = (const float*)d_in[16];
  const float* W2 = (const float*)d_in[17];
  const float* b2p = (const float*)d_in[18];
  const float* ln2w = (const float*)d_in[19];
  const float* ln2b = (const float*)d_in[20];

  int N = in_sizes[0] / HID;
  int E = in_sizes[1] / 2;
  size_t nf = (size_t)N * HID;

  float* ws = (float*)d_ws;
  size_t off = 0;
  u16* h_bf = (u16*)(ws + off); off += nf / 2;   // stays live through bd_fin
  u32* pq = (u32*)(ws + off); off += nf / 2;     // [node][64] packed q
  u32* pkv = (u32*)(ws + off); off += nf;        // [node][64]{kword,vword}
  float* skipx1 = ws + off; off += nf;           // x1 (written by bd_fin)
  float* msg = ws + off; off += nf;              // + weab below: aliased by tbf in FFN
  u32* weab = (u32*)(ws + off); off += nf;       // [node][128] packed bf16 pairs (normalized)
  u32* qweb = (u32*)(ws + off); off += nf;       // [node][128] packed bf16 qWe; reused as h2
  float* qbe = ws + off; off += (size_t)N * 8;
  int2* sorted = (int2*)(ws + off); off += (size_t)E * 2;  // {src, eid}
  int* cnt = (int*)(ws + off); off += N;
  int* offs = (int*)(ws + off); off += N;
  int* woff = (int*)(ws + off); off += N;
  int* bs = (int*)(ws + off); off += 256;
  int* bs2 = (int*)(ws + off); off += 256;
  u16* WqkvsT = (u16*)(ws + off); off += 32768;
  u16* W1T = (u16*)(ws + off); off += 32768;
  u16* W2T = (u16*)(ws + off); off += 32768;
  u16* WbdT = (u16*)(ws + off); off += 16384;
  u16* h2o = (u16*)qweb;   // h2 output (qweb dead after fused_edge)
  u16* tbf = (u16*)msg;    // FFN intermediate aliases msg+weab (dead after bd_fin)

  convert_weights<<<1092, 256, 0, stream>>>(Wq, Wk, Wv, Wskip, W1, W2, We,
                                            WqkvsT, W1T, W2T, WbdT, cnt, N);

  int ln_blocks = (N + 3) / 4;
  ln_kernel<<<ln_blocks, 256, 0, stream>>>(x, h_bf, ln1w, ln1b, N);

  dim3 gq((N + 127) / 128, 3);
  gemm_bf16<0, 128><<<gq, 256, 0, stream>>>(h_bf, WqkvsT, N, bq, bk, bv,
                                            nullptr, pq, pkv, nullptr, nullptr);

  int nb = (N + 255) / 256;
  hist_kernel<<<1024, 256, 0, stream>>>(ei + E, cnt, E);
  scan_partial<<<nb, 256, 0, stream>>>(cnt, bs, N);
  scan_bs<<<1, 256, 0, stream>>>(bs, bs2, nb);
  scan_final<<<nb, 256, 0, stream>>>(cnt, bs2, offs, woff, N);
  scatter_kernel<<<1024, 256, 0, stream>>>(ei, woff, sorted, E);

  qwe_kernel<<<1024, 256, 0, stream>>>(pq, We, be, qweb, qbe, N);

  int fe_blocks = (N + 15) / 16;  // 4 waves/block, 4 nodes/wave
  fused_edge<<<fe_blocks, 256, 0, stream>>>(offs, cnt, sorted, ea, be, pq, pkv,
                                            qweb, qbe, msg, weab, N, E);

  // bd-GEMM + skip-GEMM + finalize + LN2 fused
  dim3 ge((N + 127) / 128, 1);
  gemm_bd_fin<<<ge, 256, 0, stream>>>((const u16*)weab, WbdT, h_bf,
                                      WqkvsT + 384 * 128, N, x, msg, be, bskip,
                                      ln2w, ln2b, skipx1, h2o);

  dim3 gf1((N + 127) / 128, 4);
  gemm_bf16<1, 128><<<gf1, 256, 0, stream>>>(h2o, W1T, N, b1p, nullptr, nullptr,
                                             nullptr, nullptr, nullptr, tbf, nullptr);
  dim3 gf2((N + 127) / 128, 1);
  gemm_bf16<2, 512><<<gf2, 256, 0, stream>>>(tbf, W2T, N, b2p, nullptr, nullptr,
                                             (float*)d_out, nullptr, nullptr,
                                             nullptr, skipx1);
}

// Round 13
// 408.162 us; speedup vs baseline: 1.1394x; 1.0514x over previous
//
#include <hip/hip_runtime.h>
#include <math.h>

#define HID 128
#define EDGE_D 32
#define SC 0.36067376f  // 0.25 * log2(e)

typedef unsigned short u16;
typedef unsigned int u32;
typedef __bf16 bf16x8 __attribute__((ext_vector_type(8)));
typedef float f32x4 __attribute__((ext_vector_type(4)));
typedef u32 u32x4 __attribute__((ext_vector_type(4)));
typedef u32 u32x2 __attribute__((ext_vector_type(2)));

static __device__ __forceinline__ u16 f2bf(float f) {
  u32 u = __float_as_uint(f);
  u += 0x7fffu + ((u >> 16) & 1u);
  return (u16)(u >> 16);
}
static __device__ __forceinline__ u32 pack2(float a, float b) {
  return (u32)f2bf(a) | ((u32)f2bf(b) << 16);
}
static __device__ __forceinline__ float bflo(u32 w) { return __uint_as_float(w << 16); }
static __device__ __forceinline__ float bfhi(u32 w) { return __uint_as_float(w & 0xffff0000u); }
// all-lanes sum within each 16-lane row via DPP row rotates (pure VALU)
static __device__ __forceinline__ float grp16_sum(float x) {
  x += __int_as_float(__builtin_amdgcn_mov_dpp(__float_as_int(x), 0x128, 0xf, 0xf, true));
  x += __int_as_float(__builtin_amdgcn_mov_dpp(__float_as_int(x), 0x124, 0xf, 0xf, true));
  x += __int_as_float(__builtin_amdgcn_mov_dpp(__float_as_int(x), 0x122, 0xf, 0xf, true));
  x += __int_as_float(__builtin_amdgcn_mov_dpp(__float_as_int(x), 0x121, 0xf, 0xf, true));
  return x;
}
static __device__ __forceinline__ float wave_allreduce_sum(float v) {
#pragma unroll
  for (int off = 32; off > 0; off >>= 1) v += __shfl_xor(v, off);
  return v;
}

// ---------- LayerNorm: out_bf16 = LN(in) ----------
__global__ __launch_bounds__(256) void ln_kernel(const float* __restrict__ in,
                                                 u16* __restrict__ out,
                                                 const float* __restrict__ w,
                                                 const float* __restrict__ b, int n) {
  int row0 = blockIdx.x * 4 + (threadIdx.x >> 6);
  int lane = threadIdx.x & 63;
  int stride = gridDim.x * 4;
  for (int row = row0; row < n; row += stride) {
    const float* p = in + (size_t)row * HID;
    float a = p[lane], c = p[lane + 64];
    float s = wave_allreduce_sum(a + c);
    float s2 = wave_allreduce_sum(a * a + c * c);
    float mean = s * (1.f / 128.f);
    float var = s2 * (1.f / 128.f) - mean * mean;
    float rs = rsqrtf(var + 1e-5f);
    u16* o = out + (size_t)row * HID;
    o[lane] = f2bf((a - mean) * rs * w[lane] + b[lane]);
    o[lane + 64] = f2bf((c - mean) * rs * w[lane + 64] + b[lane + 64]);
  }
}

// ---------- weight conversion + Wfold/bfold + cnt zero-fill ----------
// WfoldT[m][k] = SC * sum_{t<16} Wq[k][hm*16+t] * We[(m&31)][hm*16+t],  hm=m>>5
// bfold[m]    = SC * sum_{t<16} bq[hm*16+t] * We[(m&31)][hm*16+t]
__global__ __launch_bounds__(256) void convert_weights(
    const float* __restrict__ Wq, const float* __restrict__ Wk,
    const float* __restrict__ Wv, const float* __restrict__ Ws,
    const float* __restrict__ W1, const float* __restrict__ W2,
    const float* __restrict__ We, const float* __restrict__ bq,
    u16* __restrict__ WqkvsT, u16* __restrict__ W1T, u16* __restrict__ W2T,
    u16* __restrict__ WbdT, u16* __restrict__ WfoldT, float* __restrict__ bfold,
    int* __restrict__ cnt, int Nn) {
  int idx = blockIdx.x * 256 + threadIdx.x;
  if (idx < 65536) {
    int m = idx >> 7, k = idx & 127;
    const float* Wm = m < 128 ? Wq : m < 256 ? Wk : m < 384 ? Wv : Ws;
    WqkvsT[idx] = f2bf(Wm[k * 128 + (m & 127)]);
  } else if (idx < 131072) {
    int j = idx - 65536;
    int m = j >> 7, k = j & 127;
    W1T[j] = f2bf(W1[k * 512 + m]);
  } else if (idx < 196608) {
    int j = idx - 131072;
    int m = j >> 9, k = j & 511;
    W2T[j] = f2bf(W2[k * 128 + m]);
  } else if (idx < 229376) {
    int j = idx - 196608;  // WbdT [128][256]
    int m = j >> 8, c = j & 255;
    WbdT[j] = ((c >> 5) == (m >> 4)) ? f2bf(We[(c & 31) * 128 + m]) : (u16)0;
  } else if (idx < 262144) {
    int j = idx - 229376;  // WfoldT [256][128]
    int m = j >> 7, k = j & 127;
    int base = (m >> 5) * 16;
    const float* wq = Wq + k * 128 + base;
    const float* we = We + (m & 31) * 128 + base;
    float s = 0.f;
#pragma unroll
    for (int t = 0; t < 16; t++) s = fmaf(wq[t], we[t], s);
    WfoldT[j] = f2bf(s * SC);
  } else if (idx < 262400) {
    int m = idx - 262144;  // bfold [256]
    int base = (m >> 5) * 16;
    const float* we = We + (m & 31) * 128 + base;
    float s = 0.f;
#pragma unroll
    for (int t = 0; t < 16; t++) s = fmaf(bq[base + t], we[t], s);
    bfold[m] = s * SC;
  } else if (idx < 262400 + Nn) {
    cnt[idx - 262400] = 0;
  }
}

// ---------- bf16 MFMA GEMM: tile 128x128, 4 waves, 2-phase double-buffered LDS ----------
#define GSTAGE(buf, kc)                                                        \
  {                                                                            \
    _Pragma("unroll") for (int i = 0; i < 2; i++) {                            \
      int idx = i * 256 + t;                                                   \
      int row = idx >> 2, c4 = idx & 3;                                        \
      __builtin_amdgcn_global_load_lds(                                        \
          (const __attribute__((address_space(1))) u32*)(A + (size_t)(r0 + row) * K + (kc) + c4 * 8), \
          (__attribute__((address_space(3))) u32*)&As[buf][idx * 8], 16, 0, 0);\
      __builtin_amdgcn_global_load_lds(                                        \
          (const __attribute__((address_space(1))) u32*)(Bt + (size_t)(c0 + row) * K + (kc) + c4 * 8), \
          (__attribute__((address_space(3))) u32*)&Bs[buf][idx * 8], 16, 0, 0);\
    }                                                                          \
  }

#define GEMM_CORE                                                              \
  constexpr int NT = K / 32;                                                   \
  GSTAGE(0, 0)                                                                 \
  __syncthreads();                                                             \
  _Pragma("unroll") for (int tt = 0; tt < NT; tt++) {                          \
    if (tt + 1 < NT) GSTAGE((tt + 1) & 1, (tt + 1) * 32)                       \
    bf16x8 a0 = *(const bf16x8*)&As[tt & 1][(w * 32 + sr) * 32 + g * 8];       \
    bf16x8 a1 = *(const bf16x8*)&As[tt & 1][(w * 32 + 16 + sr) * 32 + g * 8];  \
    _Pragma("unroll") for (int nn = 0; nn < 8; nn++) {                         \
      bf16x8 b = *(const bf16x8*)&Bs[tt & 1][(nn * 16 + sr) * 32 + g * 8];     \
      acc[0][nn] = __builtin_amdgcn_mfma_f32_16x16x32_bf16(a0, b, acc[0][nn], 0, 0, 0); \
      acc[1][nn] = __builtin_amdgcn_mfma_f32_16x16x32_bf16(a1, b, acc[1][nn], 0, 0, 0); \
    }                                                                          \
    __syncthreads();                                                           \
  }

// EPI 0: y0 -> pq packed ; y1/y2 -> pkv packed ; y3/y4 -> qweb16 (+bfold)
// EPI 1: GELU->bf16 ; EPI 2: +bias+addsrc->f32
template <int EPI, int K>
__global__ __launch_bounds__(256) void gemm_bf16(
    const u16* __restrict__ A, const u16* __restrict__ BtQ,
    const u16* __restrict__ BtF, int n,
    const float* __restrict__ bias0, const float* __restrict__ bias1,
    const float* __restrict__ bias2, const float* __restrict__ bfold,
    float* __restrict__ of0, u32* __restrict__ opq, u32* __restrict__ pkv,
    u16* __restrict__ qweb16, u16* __restrict__ ob1,
    const float* __restrict__ addsrc) {
  __shared__ u16 As[2][128 * 32];
  __shared__ u16 Bs[2][128 * 32];
  int t = threadIdx.x;
  int w = t >> 6, lane = t & 63;
  int g = lane >> 4, sr = lane & 15;
  int r0 = blockIdx.x * 128;
  int c0;
  const u16* Bt;
  if (EPI == 0 && blockIdx.y >= 3) {
    c0 = (blockIdx.y - 3) * 128;
    Bt = BtF;
  } else {
    c0 = blockIdx.y * 128;
    Bt = BtQ;
  }
  f32x4 acc[2][8];
#pragma unroll
  for (int m = 0; m < 2; m++)
#pragma unroll
    for (int nn = 0; nn < 8; nn++) acc[m][nn] = {0.f, 0.f, 0.f, 0.f};

  GEMM_CORE

  if (EPI == 0 && blockIdx.y == 0) {  // Q packed
#pragma unroll
    for (int m = 0; m < 2; m++)
#pragma unroll
      for (int nn = 0; nn < 4; nn++)
#pragma unroll
        for (int j = 0; j < 4; j++) {
          int row = r0 + w * 32 + m * 16 + g * 4 + j;
          if (row < n) {
            int cj = nn * 16 + sr;
            opq[((size_t)row << 6) + cj] =
                pack2(acc[m][nn][j] + bias0[cj], acc[m][nn + 4][j] + bias0[cj + 64]);
          }
        }
    return;
  }
  if (EPI == 0 && blockIdx.y < 3) {  // K/V packed
    const float* bp = blockIdx.y == 1 ? bias1 : bias2;
    int which = blockIdx.y - 1;
#pragma unroll
    for (int m = 0; m < 2; m++)
#pragma unroll
      for (int nn = 0; nn < 4; nn++)
#pragma unroll
        for (int j = 0; j < 4; j++) {
          int row = r0 + w * 32 + m * 16 + g * 4 + j;
          if (row < n) {
            int cj = nn * 16 + sr;
            pkv[((size_t)row << 7) + (cj << 1) + which] =
                pack2(acc[m][nn][j] + bp[cj], acc[m][nn + 4][j] + bp[cj + 64]);
          }
        }
    return;
  }
  if (EPI == 0) {  // y3/y4: qwe panels -> u16 [node][256]
    const float* bf = bfold + c0;
#pragma unroll
    for (int m = 0; m < 2; m++)
#pragma unroll
      for (int nn = 0; nn < 4; nn++)
#pragma unroll
        for (int j = 0; j < 4; j++) {
          int row = r0 + w * 32 + m * 16 + g * 4 + j;
          if (row < n) {
            int cj = nn * 16 + sr;
            u16* qrow = qweb16 + ((size_t)row << 8) + c0;
            qrow[cj] = f2bf(acc[m][nn][j] + bf[cj]);
            qrow[cj + 64] = f2bf(acc[m][nn + 4][j] + bf[cj + 64]);
          }
        }
    return;
  }
#pragma unroll
  for (int m = 0; m < 2; m++)
#pragma unroll
    for (int nn = 0; nn < 8; nn++)
#pragma unroll
      for (int j = 0; j < 4; j++) {
        int row = r0 + w * 32 + m * 16 + g * 4 + j;
        if (row < n) {
          int cj = nn * 16 + sr;
          float val = acc[m][nn][j];
          if (EPI == 1) {
            int cjg = blockIdx.y * 128 + cj;
            float v2 = val + bias0[cjg];
            v2 = 0.5f * v2 * (1.f + erff(v2 * 0.70710678118f));
            ob1[(size_t)row * 512 + cjg] = f2bf(v2);
          } else {  // EPI == 2
            of0[(size_t)row * HID + cj] = val + bias0[cj] + addsrc[(size_t)row * HID + cj];
          }
        }
      }
}

// ---------- bd-GEMM (K=256) + skip-GEMM (K=128) + finalize + LN2 ----------
__global__ __launch_bounds__(256) void gemm_bd_fin(
    const u16* __restrict__ Aw, const u16* __restrict__ BtW,
    const u16* __restrict__ Ah, const u16* __restrict__ BtS, int n,
    const float* __restrict__ x, const u32* __restrict__ msgb,
    const float* __restrict__ be, const float* __restrict__ bskip,
    const float* __restrict__ lnw, const float* __restrict__ lnb,
    float* __restrict__ x1, u16* __restrict__ h2) {
  __shared__ u16 As[2][128 * 32];
  __shared__ u16 Bs[2][128 * 32];
  int t = threadIdx.x;
  int w = t >> 6, lane = t & 63;
  int g = lane >> 4, sr = lane & 15;
  int r0 = blockIdx.x * 128;
  int c0 = 0;
  f32x4 acc[2][8];
#pragma unroll
  for (int m = 0; m < 2; m++)
#pragma unroll
    for (int nn = 0; nn < 8; nn++) acc[m][nn] = {0.f, 0.f, 0.f, 0.f};

  {
    const u16* A = Aw;
    const u16* Bt = BtW;
    constexpr int K = 256;
    GEMM_CORE
  }
  {
    const u16* A = Ah;
    const u16* Bt = BtS;
    constexpr int K = 128;
    GEMM_CORE
  }

  float becol[8], wcol[8], bcol[8], bscol[8];
#pragma unroll
  for (int nn = 0; nn < 8; nn++) {
    int c = nn * 16 + sr;
    becol[nn] = be[c];
    bscol[nn] = bskip[c];
    wcol[nn] = lnw[c];
    bcol[nn] = lnb[c];
  }
#pragma unroll
  for (int m = 0; m < 2; m++)
#pragma unroll
    for (int j = 0; j < 4; j++) {
      int row = r0 + w * 32 + m * 16 + g * 4 + j;
      if (row < n) {
        const float* xr = x + (size_t)row * HID;
        const u32* mr = msgb + ((size_t)row << 6);
        float* x1r = x1 + (size_t)row * HID;
        u32 mw[4];
#pragma unroll
        for (int nn = 0; nn < 4; nn++) mw[nn] = mr[nn * 16 + sr];
        float tv[8];
        float s = 0.f, s2 = 0.f;
#pragma unroll
        for (int nn = 0; nn < 8; nn++) {
          int c = nn * 16 + sr;
          float mval = nn < 4 ? bflo(mw[nn]) : bfhi(mw[nn - 4]);
          float t1 = xr[c] + mval + acc[m][nn][j] + becol[nn] + bscol[nn];
          tv[nn] = t1;
          s += t1;
          s2 = fmaf(t1, t1, s2);
        }
        s = grp16_sum(s);
        s2 = grp16_sum(s2);
        float mean = s * (1.f / 128.f);
        float var = s2 * (1.f / 128.f) - mean * mean;
        float rs = rsqrtf(var + 1e-5f);
        u16* h2r = h2 + (size_t)row * HID;
#pragma unroll
        for (int nn = 0; nn < 8; nn++) {
          int c = nn * 16 + sr;
          x1r[c] = tv[nn];
          h2r[c] = f2bf((tv[nn] - mean) * rs * wcol[nn] + bcol[nn]);
        }
      }
    }
}

// ---------- counting sort by dst ----------
__global__ __launch_bounds__(256) void hist_kernel(const int* __restrict__ dstp,
                                                   int* __restrict__ cnt, int E) {
  int i = blockIdx.x * blockDim.x + threadIdx.x;
  int stride = gridDim.x * blockDim.x;
  for (; i < E; i += stride) atomicAdd(&cnt[dstp[i]], 1);
}

__global__ __launch_bounds__(256) void scan_partial(const int* __restrict__ cnt,
                                                    int* __restrict__ bs, int N) {
  __shared__ int sd[256];
  int idx = blockIdx.x * 256 + threadIdx.x;
  sd[threadIdx.x] = (idx < N) ? cnt[idx] : 0;
  __syncthreads();
  for (int s = 128; s > 0; s >>= 1) {
    if (threadIdx.x < s) sd[threadIdx.x] += sd[threadIdx.x + s];
    __syncthreads();
  }
  if (threadIdx.x == 0) bs[blockIdx.x] = sd[0];
}

// scan of block-sums folded in: each block reduces bs[0..blockIdx.x) locally
__global__ __launch_bounds__(256) void scan_final(const int* __restrict__ cnt,
                                                  const int* __restrict__ bs,
                                                  int* __restrict__ offs,
                                                  int* __restrict__ woff, int N,
                                                  int nb) {
  __shared__ int sb[256];
  __shared__ int sd[256];
  int t = threadIdx.x;
  sb[t] = (t < nb && t < (int)blockIdx.x) ? bs[t] : 0;
  __syncthreads();
  for (int s = 128; s > 0; s >>= 1) {
    if (t < s) sb[t] += sb[t + s];
    __syncthreads();
  }
  int base = sb[0];
  int idx = blockIdx.x * 256 + t;
  int v = (idx < N) ? cnt[idx] : 0;
  sd[t] = v;
  __syncthreads();
  for (int s = 1; s < 256; s <<= 1) {
    int add = (t >= s) ? sd[t - s] : 0;
    __syncthreads();
    sd[t] += add;
    __syncthreads();
  }
  if (idx < N) {
    int ex = sd[t] - v + base;
    offs[idx] = ex;
    woff[idx] = ex;
  }
}

__global__ __launch_bounds__(256) void scatter_kernel(const int* __restrict__ ei,
                                                      int* __restrict__ woff,
                                                      int2* __restrict__ sorted,
                                                      int E) {
  int i = blockIdx.x * blockDim.x + threadIdx.x;
  int stride = gridDim.x * blockDim.x;
  for (; i < E; i += stride) {
    int src = ei[i];
    int dst = ei[E + i];
    int pos = atomicAdd(&woff[dst], 1);
    sorted[pos] = make_int2(src, i);
  }
}

// ---------- fused edge attention (2-deep pipeline, 4 nodes/wave) ----------
#define ISSUE4(P, base_)                                                       \
  {                                                                            \
    _Pragma("unroll") for (int jj = 0; jj < 4; jj++) {                         \
      int sj = min(base_ + jj, segn - 1);                                      \
      int sxx = __builtin_amdgcn_readlane(seRx, sj);                           \
      int syy = __builtin_amdgcn_readlane(seRy, sj);                           \
      P##kv[jj] = *(const u32x2*)(pkv + ((size_t)sxx << 7) + (lane << 1));     \
      P##ea[jj] = *(const float2*)(eaf + ((size_t)syy << 5) + 2 * sr);         \
    }                                                                          \
  }

#define COMP4(P, base_)                                                        \
  {                                                                            \
    _Pragma("unroll") for (int jj = 0; jj < 4; jj++) {                         \
      u32 kx = P##kv[jj].x, ky = P##kv[jj].y;                                  \
      float ex = P##ea[jj].x, ey = P##ea[jj].y;                                \
      float k0 = bflo(kx), k1 = bfhi(kx);                                      \
      float v0f = bflo(ky), v1f = bfhi(ky);                                    \
      float p0 = fmaf(q0C, k0, fmaf(qw0x, ex, qw0y * ey));                     \
      float p1 = fmaf(q1C, k1, fmaf(qw1x, ex, qw1y * ey));                     \
      p0 = grp16_sum(p0) + qb0C;                                               \
      p1 = grp16_sum(p1) + qb1C;                                               \
      bool val_ = (base_ + jj) < segn;                                         \
      float w1 = val_ ? __builtin_amdgcn_exp2f(p0) : 0.f;                      \
      float w2 = val_ ? __builtin_amdgcn_exp2f(p1) : 0.f;                      \
      l1 += w1;                                                                \
      l2 += w2;                                                                \
      a0 = fmaf(w1, v0f, a0);                                                  \
      a1 = fmaf(w2, v1f, a1);                                                  \
      wa00 = fmaf(w1, ex, wa00);                                               \
      wa01 = fmaf(w1, ey, wa01);                                               \
      wa10 = fmaf(w2, ex, wa10);                                               \
      wa11 = fmaf(w2, ey, wa11);                                               \
    }                                                                          \
  }

__global__ __launch_bounds__(256) void fused_edge(
    const int* __restrict__ offs, const int* __restrict__ cnt,
    const int2* __restrict__ sorted, const float* __restrict__ eaf,
    const float* __restrict__ be, const u32* __restrict__ pq,
    const u32* __restrict__ pkv, const u16* __restrict__ qweb16,
    u32* __restrict__ msgb, u32* __restrict__ weab, int Nn, int Etot) {
  int lane = threadIdx.x & 63;
  int w = threadIdx.x >> 6;
  int g = lane >> 4, sr = lane & 15;
  int wid = blockIdx.x * 4 + w;
  int nw = gridDim.x * 4;
  int per = (Nn + nw - 1) / nw;
  int n0 = wid * per;
  int n1 = min(Nn, n0 + per);
  if (n0 >= n1) return;
  int nn = n1 - n0;

  float be0 = be[lane], be1 = be[lane + 64];

  int ml = min(lane, nn - 1);
  int myBeg = offs[n0 + ml];
  int myCnt = cnt[n0 + ml];

  // prefetch node 0 state
  int beg = __builtin_amdgcn_readlane(myBeg, 0);
  int num = __builtin_amdgcn_readlane(myCnt, 0);
  int2 se2 = sorted[min(beg + min(lane, max(num - 1, 0)), Etot - 1)];
  int seCx = se2.x, seCy = se2.y;
  u32 pqC = pq[(size_t)n0 * 64 + lane];
  u32 qwb0C = *(const u32*)(qweb16 + ((size_t)n0 << 8) + g * 32 + 2 * sr);
  u32 qwb1C = *(const u32*)(qweb16 + ((size_t)n0 << 8) + (4 + g) * 32 + 2 * sr);

  for (int ni = 0; ni < nn; ni++) {
    int node = n0 + ni;
    // next-node prefetch (independent of current compute)
    int begX = 0, numX = 0, seXx = 0, seXy = 0;
    u32 pqX = 0, qwb0X = 0, qwb1X = 0;
    if (ni + 1 < nn) {
      begX = __builtin_amdgcn_readlane(myBeg, ni + 1);
      numX = __builtin_amdgcn_readlane(myCnt, ni + 1);
      int2 sx = sorted[min(begX + min(lane, max(numX - 1, 0)), Etot - 1)];
      seXx = sx.x;
      seXy = sx.y;
      pqX = pq[(size_t)(node + 1) * 64 + lane];
      qwb0X = *(const u32*)(qweb16 + ((size_t)(node + 1) << 8) + g * 32 + 2 * sr);
      qwb1X = *(const u32*)(qweb16 + ((size_t)(node + 1) << 8) + (4 + g) * 32 + 2 * sr);
    }
    float q0C = bflo(pqC) * SC, q1C = bfhi(pqC) * SC;
    float qw0x = bflo(qwb0C), qw0y = bfhi(qwb0C);
    float qw1x = bflo(qwb1C), qw1y = bfhi(qwb1C);
    // qbe computed in-register: SC * sum_{d in head} q_d * be_d
    float qb0C = grp16_sum(q0C * be0);
    float qb1C = grp16_sum(q1C * be1);
    float l1 = 0.f, l2 = 0.f, a0 = 0.f, a1 = 0.f;
    float wa00 = 0.f, wa01 = 0.f, wa10 = 0.f, wa11 = 0.f;
    if (num > 0) {
      int cb = 0;
      int seRx = seCx, seRy = seCy;
      while (true) {
        int segn = min(num - cb, 64);
        u32x2 Akv[4], Bkv[4];
        float2 Aea[4], Bea[4];
        ISSUE4(A, 0)
        for (int c = 0; c < segn; c += 8) {
          ISSUE4(B, c + 4)
          COMP4(A, c)
          ISSUE4(A, c + 8)
          COMP4(B, c + 4)
        }
        cb += 64;
        if (cb >= num) break;
        int rem = num - cb;
        int2 sn = sorted[min(beg + cb + min(lane, rem - 1), Etot - 1)];
        seRx = sn.x;
        seRy = sn.y;
      }
    }
    // epilogue: normalized packed outputs
    float inv1 = 1.f / (l1 + 1e-30f), inv2 = 1.f / (l2 + 1e-30f);
    if (num > 0) {
      msgb[((size_t)node << 6) + lane] = pack2(a0 * inv1, a1 * inv2);
    } else {  // empty segment: bd_fin adds be -> cancel it
      msgb[((size_t)node << 6) + lane] = pack2(-be0, -be1);
    }
    weab[(size_t)node * 128 + g * 16 + sr] = pack2(wa00 * inv1, wa01 * inv1);
    weab[(size_t)node * 128 + 64 + g * 16 + sr] = pack2(wa10 * inv2, wa11 * inv2);
    beg = begX;
    num = numX;
    seCx = seXx;
    seCy = seXy;
    pqC = pqX;
    qwb0C = qwb0X;
    qwb1C = qwb1X;
  }
}

extern "C" void kernel_launch(void* const* d_in, const int* in_sizes, int n_in,
                              void* d_out, int out_size, void* d_ws, size_t ws_size,
                              hipStream_t stream) {
  const float* x = (const float*)d_in[0];
  const int* ei = (const int*)d_in[1];
  const float* ea = (const float*)d_in[2];
  const float* Wq = (const float*)d_in[3];
  const float* bq = (const float*)d_in[4];
  const float* Wk = (const float*)d_in[5];
  const float* bk = (const float*)d_in[6];
  const float* Wv = (const float*)d_in[7];
  const float* bv = (const float*)d_in[8];
  const float* We = (const float*)d_in[9];
  const float* be = (const float*)d_in[10];
  const float* Wskip = (const float*)d_in[11];
  const float* bskip = (const float*)d_in[12];
  const float* ln1w = (const float*)d_in[13];
  const float* ln1b = (const float*)d_in[14];
  const float* W1 = (const float*)d_in[15];
  const float* b1p = (const float*)d_in[16];
  const float* W2 = (const float*)d_in[17];
  const float* b2p = (const float*)d_in[18];
  const float* ln2w = (const float*)d_in[19];
  const float* ln2b = (const float*)d_in[20];

  int N = in_sizes[0] / HID;
  int E = in_sizes[1] / 2;
  size_t nf = (size_t)N * HID;

  float* ws = (float*)d_ws;
  size_t off = 0;
  u16* h_bf = (u16*)(ws + off); off += nf / 2;   // live through bd_fin
  u32* pq = (u32*)(ws + off); off += nf / 2;     // [node][64] packed q; reused as h2
  u32* pkv = (u32*)(ws + off); off += nf;        // [node][64]{kword,vword}
  float* skipx1 = ws + off; off += nf;           // x1 (written by bd_fin)
  u32* msgb = (u32*)(ws + off); off += nf / 2;   // [node][64] packed msg (normalized)
  u32* weab = (u32*)(ws + off); off += nf;       // [node][128] packed wea (normalized)
  u16* qweb16 = (u16*)(ws + off); off += nf;     // [node][256] bf16 qwe (N*512B = nf floats)
  int2* sorted = (int2*)(ws + off); off += (size_t)E * 2;  // {src, eid}
  int* cnt = (int*)(ws + off); off += N;
  int* offs = (int*)(ws + off); off += N;
  int* woff = (int*)(ws + off); off += N;
  int* bs = (int*)(ws + off); off += 256;
  u16* WqkvsT = (u16*)(ws + off); off += 32768;
  u16* W1T = (u16*)(ws + off); off += 32768;
  u16* W2T = (u16*)(ws + off); off += 32768;
  u16* WbdT = (u16*)(ws + off); off += 16384;
  u16* WfoldT = (u16*)(ws + off); off += 16384;
  float* bfold = ws + off; off += 256;
  u16* h2o = (u16*)pq;      // h2 output (pq dead after fused_edge)
  u16* tbf = (u16*)msgb;    // FFN intermediate aliases msgb+weab+qweb16 (dead after bd_fin)

  convert_weights<<<1221, 256, 0, stream>>>(Wq, Wk, Wv, Wskip, W1, W2, We, bq,
                                            WqkvsT, W1T, W2T, WbdT, WfoldT,
                                            bfold, cnt, N);

  int ln_blocks = (N + 3) / 4;
  ln_kernel<<<ln_blocks, 256, 0, stream>>>(x, h_bf, ln1w, ln1b, N);

  dim3 gq((N + 127) / 128, 5);
  gemm_bf16<0, 128><<<gq, 256, 0, stream>>>(h_bf, WqkvsT, WfoldT, N, bq, bk, bv,
                                            bfold, nullptr, pq, pkv, qweb16,
                                            nullptr, nullptr);

  int nb = (N + 255) / 256;
  hist_kernel<<<1024, 256, 0, stream>>>(ei + E, cnt, E);
  scan_partial<<<nb, 256, 0, stream>>>(cnt, bs, N);
  scan_final<<<nb, 256, 0, stream>>>(cnt, bs, offs, woff, N, nb);
  scatter_kernel<<<1024, 256, 0, stream>>>(ei, woff, sorted, E);

  int fe_blocks = (N + 15) / 16;  // 4 waves/block, 4 nodes/wave
  fused_edge<<<fe_blocks, 256, 0, stream>>>(offs, cnt, sorted, ea, be, pq, pkv,
                                            qweb16, msgb, weab, N, E);

  // bd-GEMM + skip-GEMM + finalize + LN2 fused
  dim3 ge((N + 127) / 128, 1);
  gemm_bd_fin<<<ge, 256, 0, stream>>>((const u16*)weab, WbdT, h_bf,
                                      WqkvsT + 384 * 128, N, x, msgb, be, bskip,
                                      ln2w, ln2b, skipx1, h2o);

  dim3 gf1((N + 127) / 128, 4);
  gemm_bf16<1, 128><<<gf1, 256, 0, stream>>>(h2o, W1T, nullptr, N, b1p, nullptr,
                                             nullptr, nullptr, nullptr, nullptr,
                                             nullptr, nullptr, tbf, nullptr);
  dim3 gf2((N + 127) / 128, 1);
  gemm_bf16<2, 512><<<gf2, 256, 0, stream>>>(tbf, W2T, nullptr, N, b2p, nullptr,
                                             nullptr, nullptr, (float*)d_out,
                                             nullptr, nullptr, nullptr, nullptr,
                                             skipx1);
}